// Round 6
// baseline (433.406 us; speedup 1.0000x reference)
//
#include <hip/hip_runtime.h>
#include <hip/hip_bf16.h>

// Problem constants (B,N,D,H = 4,2048,512,8; DK=64)
// fp32 inputs / fp32 output; bf16 intermediates in ws (33.5 MB, proven fit).
#define B_  4
#define N_  2048
#define D_  512
#define H_  8

typedef unsigned short u16;
typedef __attribute__((ext_vector_type(8))) unsigned short ushort8;
typedef __attribute__((ext_vector_type(4))) unsigned short us4;   // 'ushort4' collides with HIP types
typedef __attribute__((ext_vector_type(8))) short short8;
typedef __attribute__((ext_vector_type(4))) float float4v;

__device__ __forceinline__ float bf2f(u16 u) {
    union { unsigned int i; float f; } v;
    v.i = ((unsigned int)u) << 16;
    return v.f;
}
__device__ __forceinline__ u16 f2bf(float f) {          // RNE
    union { float f; unsigned int i; } v;
    v.f = f;
    unsigned int r = v.i + 0x7FFFu + ((v.i >> 16) & 1u);
    return (u16)(r >> 16);
}
__device__ __forceinline__ u16 f2bf_fast(float f) {     // round-half-up, 2 VALU ops
    union { float f; unsigned int i; } v;
    v.f = f;
    return (u16)((v.i + 0x8000u) >> 16);
}

// async global->LDS, 16B/lane, dest = wave-uniform base + lane*16 (m104 rule)
__device__ __forceinline__ void gload_lds16(const void* g, void* l) {
    __builtin_amdgcn_global_load_lds(
        (const __attribute__((address_space(1))) unsigned int*)g,
        (__attribute__((address_space(3))) unsigned int*)l, 16, 0, 0);
}

// ---------------------------------------------------------------------------
// MFMA GEMM: C[M,512] = X[M,512] @ W[512,512]^T(fp32) + bias(fp32)
// IN_BF16: X bf16 (ws) via global_load_lds (As rows unpadded, STRA=32);
//          else X fp32, VALU-convert staging (STRA=40).
// OUT_BF16: C bf16 (ws); z==2 stores TRANSPOSED per batch -> Vpt[b][e][n].
// 128x128 tile, 256 thr = 4 waves (each 64x64 = 4x4 MFMA 16x16x32), BK=32.
// ---------------------------------------------------------------------------
template <bool IN_BF16, bool OUT_BF16, int STRA>
__global__ __launch_bounds__(256) void proj_mfma(
    const void* __restrict__ X0v, const void* __restrict__ X1v,
    const void* __restrict__ X2v, const float* __restrict__ W,
    const float* __restrict__ bias, void* __restrict__ C0v, int M)
{
    __shared__ u16 As[128][STRA];
    __shared__ u16 Bs[128][40];

    const int t = threadIdx.x;
    const int z = blockIdx.z;
    const void* Xv = (z == 0) ? X0v : ((z == 1) ? X1v : X2v);
    const int e0 = blockIdx.x * 128;
    const int m0 = blockIdx.y * 128;
    const int w = t >> 6, l = t & 63;
    const int lane16 = l & 15, quad = l >> 4;
    const int wr = (w >> 1) * 64;
    const int wc = (w & 1) * 64;

    float4v acc[4][4];
    #pragma unroll
    for (int i = 0; i < 4; ++i)
        #pragma unroll
        for (int j = 0; j < 4; ++j)
            acc[i][j] = (float4v){0.f, 0.f, 0.f, 0.f};

    for (int k0 = 0; k0 < 512; k0 += 32) {
        __syncthreads();

        if (IN_BF16) {
            const u16* X = (const u16*)Xv;
            #pragma unroll
            for (int i = 0; i < 2; ++i) {
                int r0 = w * 32 + i * 16;
                gload_lds16(X + (size_t)(m0 + r0 + (l >> 2)) * 512 + k0 + (l & 3) * 8,
                            &As[r0][0]);
            }
        } else {
            const float* X = (const float*)Xv;
            #pragma unroll
            for (int i = 0; i < 2; ++i) {
                int v   = t + 256 * i;
                int row = v >> 2;
                int c8  = (v & 3) * 8;
                const float* xp = X + (size_t)(m0 + row) * 512 + k0 + c8;
                float4v x0 = *(const float4v*)xp;
                float4v x1 = *(const float4v*)(xp + 4);
                ushort8 o;
                #pragma unroll
                for (int j = 0; j < 4; ++j) {
                    o[j]     = f2bf_fast(x0[j]);
                    o[j + 4] = f2bf_fast(x1[j]);
                }
                *(ushort8*)&As[row][c8] = o;
            }
        }
        #pragma unroll
        for (int i = 0; i < 2; ++i) {
            int v   = t + 256 * i;
            int row = v >> 2;
            int c8  = (v & 3) * 8;
            const float* wp = W + (size_t)(e0 + row) * 512 + k0 + c8;
            float4v w0 = *(const float4v*)wp;
            float4v w1 = *(const float4v*)(wp + 4);
            ushort8 o;
            #pragma unroll
            for (int j = 0; j < 4; ++j) {
                o[j]     = f2bf_fast(w0[j]);
                o[j + 4] = f2bf_fast(w1[j]);
            }
            *(ushort8*)&Bs[row][c8] = o;
        }
        __syncthreads();

        short8 af[4], bfr[4];
        #pragma unroll
        for (int i = 0; i < 4; ++i)
            af[i] = *(const short8*)&As[wr + i * 16 + lane16][quad * 8];
        #pragma unroll
        for (int j = 0; j < 4; ++j)
            bfr[j] = *(const short8*)&Bs[wc + j * 16 + lane16][quad * 8];
        #pragma unroll
        for (int i = 0; i < 4; ++i)
            #pragma unroll
            for (int j = 0; j < 4; ++j)
                acc[i][j] = __builtin_amdgcn_mfma_f32_16x16x32_bf16(
                    af[i], bfr[j], acc[i][j], 0, 0, 0);
    }

    float bj[4];
    #pragma unroll
    for (int j = 0; j < 4; ++j) bj[j] = bias[e0 + wc + j * 16 + lane16];

    if (OUT_BF16) {
        if (z == 2) {
            u16* C = (u16*)C0v + 2 * (size_t)M * D_;
            #pragma unroll
            for (int i = 0; i < 4; ++i) {
                int mrow = m0 + wr + i * 16 + quad * 4;
                int bb = mrow >> 11, nb = mrow & (N_ - 1);
                #pragma unroll
                for (int j = 0; j < 4; ++j) {
                    int e = e0 + wc + j * 16 + lane16;
                    us4 o;
                    #pragma unroll
                    for (int r = 0; r < 4; ++r) o[r] = f2bf(acc[i][j][r] + bj[j]);
                    *(us4*)(C + (size_t)(bb * D_ + e) * N_ + nb) = o;
                }
            }
        } else {
            u16* C = (u16*)C0v + (size_t)z * (size_t)M * D_;
            #pragma unroll
            for (int i = 0; i < 4; ++i)
                #pragma unroll
                for (int j = 0; j < 4; ++j) {
                    int e = e0 + wc + j * 16 + lane16;
                    #pragma unroll
                    for (int r = 0; r < 4; ++r) {
                        int mrow = m0 + wr + i * 16 + quad * 4 + r;
                        C[(size_t)mrow * D_ + e] = f2bf(acc[i][j][r] + bj[j]);
                    }
                }
        }
    } else {
        float* C = (float*)C0v;
        #pragma unroll
        for (int i = 0; i < 4; ++i)
            #pragma unroll
            for (int j = 0; j < 4; ++j) {
                int e = e0 + wc + j * 16 + lane16;
                #pragma unroll
                for (int r = 0; r < 4; ++r) {
                    int mrow = m0 + wr + i * 16 + quad * 4 + r;
                    C[(size_t)mrow * D_ + e] = acc[i][j][r] + bj[j];
                }
            }
    }
}

// ---------------------------------------------------------------------------
// MFMA attention v2: softmax over HEADS, fully in-register.
// Block = 16 q-rows, 4 waves. Iteration = 64 m values:
//   phase 1 (per wave, m-subtile w): QK^T for ALL 8 heads -> 8 C-layout accs;
//     for fixed (n,m) the 8 head scores live in one lane -> register softmax.
//   P -> LDS (layout [h][n][m64], stride 68: conflict-free writes).
//   phase 2 (per wave, heads {2w,2w+1}): PV over all 64 m (k=2x32 MFMA).
// K/V fragments read directly from global (L2-resident slabs).
// 2 barriers per 64-m iteration (was ~14). grid = (N/16, B).
// Qp,Kp: [b][n][d] bf16. Vpt: [b][d][n] bf16. A: [b][n][d] bf16.
// ---------------------------------------------------------------------------
__global__ __launch_bounds__(256, 2) void attn_mfma(
    const u16* __restrict__ Qp, const u16* __restrict__ Kp,
    const u16* __restrict__ Vpt, u16* __restrict__ A)
{
    __shared__ u16 Ps[8][16][68];   // probs [h][n][m64], 17,408 B

    const int t  = threadIdx.x;
    const int w  = t >> 6;
    const int l  = t & 63;
    const int lane16 = l & 15;
    const int quad   = l >> 4;
    const int b  = blockIdx.y;
    const int n0 = blockIdx.x * 16;
    const int h0 = w * 2;           // PV heads {h0, h0+1}

    // Q fragments: all 8 heads, A-operand layout, persistent (64 VGPRs)
    short8 qfrag[8][2];
    {
        const u16* qb = Qp + ((size_t)(b * N_ + n0 + lane16) * D_ + quad * 8);
        #pragma unroll
        for (int h = 0; h < 8; ++h)
            #pragma unroll
            for (int dc = 0; dc < 2; ++dc)
                qfrag[h][dc] = *(const short8*)(qb + h * 64 + dc * 32);
    }

    // K base for this wave's m-subtile (m = m0 + w*16 + lane16)
    const u16* kb = Kp + ((size_t)(b * N_ + w * 16 + lane16) * D_ + quad * 8);
    // V base: row d = h0*64 + lane16 (dt/hh offsets added per use)
    const u16* vb = Vpt + ((size_t)(b * D_ + h0 * 64 + lane16) * N_ + quad * 8);

    float4v aacc[2][4];
    #pragma unroll
    for (int hh = 0; hh < 2; ++hh)
        #pragma unroll
        for (int dt = 0; dt < 4; ++dt)
            aacc[hh][dt] = (float4v){0.f, 0.f, 0.f, 0.f};

    for (int m0 = 0; m0 < N_; m0 += 64) {
        // ---- phase 1: QK^T all 8 heads for m-subtile w (no LDS) ----
        float4v sacc[8];
        #pragma unroll
        for (int h = 0; h < 8; ++h) sacc[h] = (float4v){0.f, 0.f, 0.f, 0.f};

        const u16* kp = kb + (size_t)m0 * D_;
        #pragma unroll
        for (int h = 0; h < 8; ++h)
            #pragma unroll
            for (int dc = 0; dc < 2; ++dc) {
                short8 kf = *(const short8*)(kp + h * 64 + dc * 32);
                sacc[h] = __builtin_amdgcn_mfma_f32_16x16x32_bf16(
                    qfrag[h][dc], kf, sacc[h], 0, 0, 0);
            }

        // ---- in-register softmax over heads; this lane owns 4 (n,m) pairs ----
        float p[8][4];
        #pragma unroll
        for (int r = 0; r < 4; ++r) {
            float sum = 0.f;
            #pragma unroll
            for (int h = 0; h < 8; ++h) {
                p[h][r] = __expf(sacc[h][r] * 0.125f);   // 1/sqrt(64)
                sum += p[h][r];
            }
            float inv = 1.f / sum;
            #pragma unroll
            for (int h = 0; h < 8; ++h) p[h][r] *= inv;
        }

        __syncthreads();   // WAR: prev iteration's PV reads of Ps complete

        // ---- write P: Ps[h][n=quad*4+r][mloc=w*16+lane16] (conflict-free) ----
        #pragma unroll
        for (int h = 0; h < 8; ++h)
            #pragma unroll
            for (int r = 0; r < 4; ++r)
                Ps[h][quad * 4 + r][w * 16 + lane16] = f2bf(p[h][r]);

        __syncthreads();   // P visible

        // ---- phase 2: PV for heads {h0,h0+1} over all 64 m ----
        const u16* vp = vb + m0;
        #pragma unroll
        for (int hh = 0; hh < 2; ++hh)
            #pragma unroll
            for (int ko = 0; ko < 2; ++ko) {
                short8 pf = *(const short8*)(&Ps[h0 + hh][lane16][ko * 32 + quad * 8]);
                #pragma unroll
                for (int dt = 0; dt < 4; ++dt) {
                    short8 vf = *(const short8*)(vp +
                        ((size_t)(hh * 64 + dt * 16) * N_) + ko * 32);
                    aacc[hh][dt] = __builtin_amdgcn_mfma_f32_16x16x32_bf16(
                        pf, vf, aacc[hh][dt], 0, 0, 0);
                }
            }
    }

    // ---- store combined-head A (bf16) ----
    #pragma unroll
    for (int hh = 0; hh < 2; ++hh)
        #pragma unroll
        for (int dt = 0; dt < 4; ++dt)
            #pragma unroll
            for (int r = 0; r < 4; ++r) {
                const int n = n0 + quad * 4 + r;
                const int d = (h0 + hh) * 64 + dt * 16 + lane16;
                A[(size_t)(b * N_ + n) * D_ + d] = f2bf(aacc[hh][dt][r]);
            }
}

// ---------------------------------------------------------------------------
extern "C" void kernel_launch(void* const* d_in, const int* in_sizes, int n_in,
                              void* d_out, int out_size, void* d_ws, size_t ws_size,
                              hipStream_t stream)
{
    const float* Q  = (const float*)d_in[0];
    const float* K  = (const float*)d_in[1];
    const float* V  = (const float*)d_in[2];
    const float* Wq = (const float*)d_in[3];
    const float* bq = (const float*)d_in[4];
    const float* Wo = (const float*)d_in[5];
    const float* bo = (const float*)d_in[6];
    float* out = (float*)d_out;
    u16*   ws  = (u16*)d_ws;

    const size_t NBD = (size_t)B_ * N_ * D_;   // 4,194,304
    u16* Qp  = ws;                // [b][n][d]
    u16* Kp  = ws + NBD;          // [b][n][d]
    u16* Vpt = ws + 2 * NBD;      // [b][d][n]
    u16* Ap  = ws + 3 * NBD;      // [b][n][d]

    const int M = B_ * N_;        // 8192

    // 1) shared-weight projections (source bug: Wq/bq for Q, K, AND V) -> bf16 ws
    dim3 gp(D_ / 128, M / 128, 3);
    proj_mfma<false, true, 40><<<gp, dim3(256), 0, stream>>>(Q, K, V, Wq, bq, Qp, M);

    // 2) MFMA attention v2 (in-register heads-softmax)
    dim3 ga(N_ / 16, B_);
    attn_mfma<<<ga, dim3(256), 0, stream>>>(Qp, Kp, Vpt, Ap);

    // 3) output projection: bf16 Ap @ Wo^T + bo -> fp32 d_out
    dim3 go(D_ / 128, M / 128, 1);
    proj_mfma<true, false, 32><<<go, dim3(256), 0, stream>>>(Ap, Ap, Ap, Wo, bo, out, M);
}

// Round 7
// 426.564 us; speedup vs baseline: 1.0160x; 1.0160x over previous
//
#include <hip/hip_runtime.h>
#include <hip/hip_bf16.h>

// Problem constants (B,N,D,H = 4,2048,512,8; DK=64)
// fp32 inputs / fp32 output; bf16 intermediates in ws.
// Big path (ws >= 43 MB): W pre-converted to bf16; attn m-split x2 into two
// bf16 partial-A buffers summed by stage-3 staging. Fallback: R5-footprint.
#define B_  4
#define N_  2048
#define D_  512
#define H_  8

typedef unsigned short u16;
typedef __attribute__((ext_vector_type(8))) unsigned short ushort8;
typedef __attribute__((ext_vector_type(4))) unsigned short us4;
typedef __attribute__((ext_vector_type(8))) short short8;
typedef __attribute__((ext_vector_type(4))) float float4v;

__device__ __forceinline__ float bf2f(u16 u) {
    union { unsigned int i; float f; } v;
    v.i = ((unsigned int)u) << 16;
    return v.f;
}
__device__ __forceinline__ u16 f2bf(float f) {          // RNE
    union { float f; unsigned int i; } v;
    v.f = f;
    unsigned int r = v.i + 0x7FFFu + ((v.i >> 16) & 1u);
    return (u16)(r >> 16);
}
__device__ __forceinline__ u16 f2bf_fast(float f) {     // round-half-up
    union { float f; unsigned int i; } v;
    v.f = f;
    return (u16)((v.i + 0x8000u) >> 16);
}

// async global->LDS, 16B/lane, dest = wave-uniform base + lane*16 (m104 rule)
__device__ __forceinline__ void gload_lds16(const void* g, void* l) {
    __builtin_amdgcn_global_load_lds(
        (const __attribute__((address_space(1))) unsigned int*)g,
        (__attribute__((address_space(3))) unsigned int*)l, 16, 0, 0);
}

// ---------------------------------------------------------------------------
// wconv: Wq,Wo fp32 -> bf16 (RNE), out = [Wqb | Wob]. grid (128, 2) x 256.
// ---------------------------------------------------------------------------
__global__ __launch_bounds__(256) void wconv(
    const float* __restrict__ Wq, const float* __restrict__ Wo,
    u16* __restrict__ out)
{
    const int idx = (blockIdx.x * 256 + threadIdx.x) * 8;
    const float* src = blockIdx.y ? Wo : Wq;
    u16* dst = out + (size_t)blockIdx.y * (D_ * D_) + idx;
    float4v a = *(const float4v*)(src + idx);
    float4v b = *(const float4v*)(src + idx + 4);
    ushort8 o;
    #pragma unroll
    for (int j = 0; j < 4; ++j) { o[j] = f2bf(a[j]); o[j + 4] = f2bf(b[j]); }
    *(ushort8*)dst = o;
}

// ---------------------------------------------------------------------------
// MFMA GEMM: C[M,512] = X @ W^T + bias.
// INK: 0 = X fp32 (VALU convert), 1 = X bf16 (global_load_lds),
//      2 = X = X0+X1 bf16 partials (convert-sum staging).
// WB16: W bf16 via global_load_lds, else fp32 VALU convert.
// OUTB16: C bf16; z==2 stores transposed Vpt[b][e][n]. Else C fp32.
// 128x128 tile, 4 waves x (64x64 = 4x4 MFMA 16x16x32), BK=32. As/Bs unpadded.
// ---------------------------------------------------------------------------
template <int INK, bool WB16, bool OUTB16>
__global__ __launch_bounds__(256) void proj_mfma(
    const void* __restrict__ X0v, const void* __restrict__ X1v,
    const void* __restrict__ X2v, const void* __restrict__ Wv,
    const float* __restrict__ bias, void* __restrict__ C0v, int M)
{
    __shared__ u16 As[128][32];
    __shared__ u16 Bs[128][32];

    const int t = threadIdx.x;
    const int z = blockIdx.z;
    const void* Xv = (z == 0) ? X0v : ((z == 1) ? X1v : X2v);
    const int e0 = blockIdx.x * 128;
    const int m0 = blockIdx.y * 128;
    const int w = t >> 6, l = t & 63;
    const int lane16 = l & 15, quad = l >> 4;
    const int wr = (w >> 1) * 64;
    const int wc = (w & 1) * 64;

    float4v acc[4][4];
    #pragma unroll
    for (int i = 0; i < 4; ++i)
        #pragma unroll
        for (int j = 0; j < 4; ++j)
            acc[i][j] = (float4v){0.f, 0.f, 0.f, 0.f};

    for (int k0 = 0; k0 < 512; k0 += 32) {
        __syncthreads();

        // ---- stage A tile ----
        if (INK == 1) {
            const u16* X = (const u16*)Xv;
            #pragma unroll
            for (int i = 0; i < 2; ++i) {
                int r0 = w * 32 + i * 16;
                gload_lds16(X + (size_t)(m0 + r0 + (l >> 2)) * 512 + k0 + (l & 3) * 8,
                            &As[r0][0]);
            }
        } else if (INK == 0) {
            const float* X = (const float*)Xv;
            #pragma unroll
            for (int i = 0; i < 2; ++i) {
                int v   = t + 256 * i;
                int row = v >> 2;
                int c8  = (v & 3) * 8;
                const float* xp = X + (size_t)(m0 + row) * 512 + k0 + c8;
                float4v x0 = *(const float4v*)xp;
                float4v x1 = *(const float4v*)(xp + 4);
                ushort8 o;
                #pragma unroll
                for (int j = 0; j < 4; ++j) {
                    o[j]     = f2bf_fast(x0[j]);
                    o[j + 4] = f2bf_fast(x1[j]);
                }
                *(ushort8*)&As[row][c8] = o;
            }
        } else {  // INK == 2: sum of two bf16 partials
            const u16* P0 = (const u16*)X0v;
            const u16* P1 = (const u16*)X1v;
            #pragma unroll
            for (int i = 0; i < 2; ++i) {
                int v   = t + 256 * i;
                int row = v >> 2;
                int c8  = (v & 3) * 8;
                size_t gi = (size_t)(m0 + row) * 512 + k0 + c8;
                ushort8 a = *(const ushort8*)(P0 + gi);
                ushort8 b = *(const ushort8*)(P1 + gi);
                ushort8 o;
                #pragma unroll
                for (int j = 0; j < 8; ++j) o[j] = f2bf(bf2f(a[j]) + bf2f(b[j]));
                *(ushort8*)&As[row][c8] = o;
            }
        }

        // ---- stage B tile (W) ----
        if (WB16) {
            const u16* Wb = (const u16*)Wv;
            #pragma unroll
            for (int i = 0; i < 2; ++i) {
                int r0 = w * 32 + i * 16;
                gload_lds16(Wb + (size_t)(e0 + r0 + (l >> 2)) * 512 + k0 + (l & 3) * 8,
                            &Bs[r0][0]);
            }
        } else {
            const float* W = (const float*)Wv;
            #pragma unroll
            for (int i = 0; i < 2; ++i) {
                int v   = t + 256 * i;
                int row = v >> 2;
                int c8  = (v & 3) * 8;
                const float* wp = W + (size_t)(e0 + row) * 512 + k0 + c8;
                float4v w0 = *(const float4v*)wp;
                float4v w1 = *(const float4v*)(wp + 4);
                ushort8 o;
                #pragma unroll
                for (int j = 0; j < 4; ++j) {
                    o[j]     = f2bf_fast(w0[j]);
                    o[j + 4] = f2bf_fast(w1[j]);
                }
                *(ushort8*)&Bs[row][c8] = o;
            }
        }
        __syncthreads();

        short8 af[4], bfr[4];
        #pragma unroll
        for (int i = 0; i < 4; ++i)
            af[i] = *(const short8*)&As[wr + i * 16 + lane16][quad * 8];
        #pragma unroll
        for (int j = 0; j < 4; ++j)
            bfr[j] = *(const short8*)&Bs[wc + j * 16 + lane16][quad * 8];
        #pragma unroll
        for (int i = 0; i < 4; ++i)
            #pragma unroll
            for (int j = 0; j < 4; ++j)
                acc[i][j] = __builtin_amdgcn_mfma_f32_16x16x32_bf16(
                    af[i], bfr[j], acc[i][j], 0, 0, 0);
    }

    float bj[4];
    #pragma unroll
    for (int j = 0; j < 4; ++j) bj[j] = bias[e0 + wc + j * 16 + lane16];

    if (OUTB16) {
        if (z == 2) {   // transposed store: Vpt[b][e][n]
            u16* C = (u16*)C0v + 2 * (size_t)M * D_;
            #pragma unroll
            for (int i = 0; i < 4; ++i) {
                int mrow = m0 + wr + i * 16 + quad * 4;
                int bb = mrow >> 11, nb = mrow & (N_ - 1);
                #pragma unroll
                for (int j = 0; j < 4; ++j) {
                    int e = e0 + wc + j * 16 + lane16;
                    us4 o;
                    #pragma unroll
                    for (int r = 0; r < 4; ++r) o[r] = f2bf(acc[i][j][r] + bj[j]);
                    *(us4*)(C + (size_t)(bb * D_ + e) * N_ + nb) = o;
                }
            }
        } else {
            u16* C = (u16*)C0v + (size_t)z * (size_t)M * D_;
            #pragma unroll
            for (int i = 0; i < 4; ++i)
                #pragma unroll
                for (int j = 0; j < 4; ++j) {
                    int e = e0 + wc + j * 16 + lane16;
                    #pragma unroll
                    for (int r = 0; r < 4; ++r) {
                        int mrow = m0 + wr + i * 16 + quad * 4 + r;
                        C[(size_t)mrow * D_ + e] = f2bf(acc[i][j][r] + bj[j]);
                    }
                }
        }
    } else {
        float* C = (float*)C0v;
        #pragma unroll
        for (int i = 0; i < 4; ++i)
            #pragma unroll
            for (int j = 0; j < 4; ++j) {
                int e = e0 + wc + j * 16 + lane16;
                #pragma unroll
                for (int r = 0; r < 4; ++r) {
                    int mrow = m0 + wr + i * 16 + quad * 4 + r;
                    C[(size_t)mrow * D_ + e] = acc[i][j][r] + bj[j];
                }
            }
    }
}

// ---------------------------------------------------------------------------
// MFMA attention, softmax over HEADS, in-register (R6 structure) + m-SPLIT.
// grid (N/16, B, SPLIT); block z handles m in [z*N/SPLIT, (z+1)*N/SPLIT),
// writing bf16 partial A to Abase + z*B*N*D. SPLIT=1 == full reduction.
// ---------------------------------------------------------------------------
template <int SPLIT>
__global__ __launch_bounds__(256, 4) void attn_mfma(
    const u16* __restrict__ Qp, const u16* __restrict__ Kp,
    const u16* __restrict__ Vpt, u16* __restrict__ A0)
{
    __shared__ u16 Ps[8][16][68];   // probs [h][n][m64], 17,408 B

    const int t  = threadIdx.x;
    const int w  = t >> 6;
    const int l  = t & 63;
    const int lane16 = l & 15;
    const int quad   = l >> 4;
    const int b  = blockIdx.y;
    const int n0 = blockIdx.x * 16;
    const int h0 = w * 2;           // PV heads {h0, h0+1}
    const int seg = N_ / SPLIT;
    const int mbeg = blockIdx.z * seg;
    u16* A = A0 + (size_t)blockIdx.z * ((size_t)B_ * N_ * D_);

    // Q fragments: all 8 heads, A-operand layout, persistent
    short8 qfrag[8][2];
    {
        const u16* qb = Qp + ((size_t)(b * N_ + n0 + lane16) * D_ + quad * 8);
        #pragma unroll
        for (int h = 0; h < 8; ++h)
            #pragma unroll
            for (int dc = 0; dc < 2; ++dc)
                qfrag[h][dc] = *(const short8*)(qb + h * 64 + dc * 32);
    }

    const u16* kb = Kp + ((size_t)(b * N_ + w * 16 + lane16) * D_ + quad * 8);
    const u16* vb = Vpt + ((size_t)(b * D_ + h0 * 64 + lane16) * N_ + quad * 8);

    float4v aacc[2][4];
    #pragma unroll
    for (int hh = 0; hh < 2; ++hh)
        #pragma unroll
        for (int dt = 0; dt < 4; ++dt)
            aacc[hh][dt] = (float4v){0.f, 0.f, 0.f, 0.f};

    for (int m0 = mbeg; m0 < mbeg + seg; m0 += 64) {
        // ---- QK^T all 8 heads for m-subtile w ----
        float4v sacc[8];
        #pragma unroll
        for (int h = 0; h < 8; ++h) sacc[h] = (float4v){0.f, 0.f, 0.f, 0.f};

        const u16* kp = kb + (size_t)m0 * D_;
        #pragma unroll
        for (int h = 0; h < 8; ++h)
            #pragma unroll
            for (int dc = 0; dc < 2; ++dc) {
                short8 kf = *(const short8*)(kp + h * 64 + dc * 32);
                sacc[h] = __builtin_amdgcn_mfma_f32_16x16x32_bf16(
                    qfrag[h][dc], kf, sacc[h], 0, 0, 0);
            }

        // ---- in-register softmax over heads (4 (n,m) pairs per lane) ----
        float p[8][4];
        #pragma unroll
        for (int r = 0; r < 4; ++r) {
            float sum = 0.f;
            #pragma unroll
            for (int h = 0; h < 8; ++h) {
                p[h][r] = __expf(sacc[h][r] * 0.125f);   // 1/sqrt(64)
                sum += p[h][r];
            }
            float inv = 1.f / sum;
            #pragma unroll
            for (int h = 0; h < 8; ++h) p[h][r] *= inv;
        }

        __syncthreads();   // WAR on Ps

        #pragma unroll
        for (int h = 0; h < 8; ++h)
            #pragma unroll
            for (int r = 0; r < 4; ++r)
                Ps[h][quad * 4 + r][w * 16 + lane16] = f2bf(p[h][r]);

        __syncthreads();   // P visible

        // ---- PV for heads {h0,h0+1} over 64 m ----
        const u16* vp = vb + m0;
        #pragma unroll
        for (int hh = 0; hh < 2; ++hh)
            #pragma unroll
            for (int ko = 0; ko < 2; ++ko) {
                short8 pf = *(const short8*)(&Ps[h0 + hh][lane16][ko * 32 + quad * 8]);
                #pragma unroll
                for (int dt = 0; dt < 4; ++dt) {
                    short8 vf = *(const short8*)(vp +
                        ((size_t)(hh * 64 + dt * 16) * N_) + ko * 32);
                    aacc[hh][dt] = __builtin_amdgcn_mfma_f32_16x16x32_bf16(
                        pf, vf, aacc[hh][dt], 0, 0, 0);
                }
            }
    }

    // ---- store (partial) A, bf16 ----
    #pragma unroll
    for (int hh = 0; hh < 2; ++hh)
        #pragma unroll
        for (int dt = 0; dt < 4; ++dt)
            #pragma unroll
            for (int r = 0; r < 4; ++r) {
                const int n = n0 + quad * 4 + r;
                const int d = (h0 + hh) * 64 + dt * 16 + lane16;
                A[(size_t)(b * N_ + n) * D_ + d] = f2bf(aacc[hh][dt][r]);
            }
}

// ---------------------------------------------------------------------------
extern "C" void kernel_launch(void* const* d_in, const int* in_sizes, int n_in,
                              void* d_out, int out_size, void* d_ws, size_t ws_size,
                              hipStream_t stream)
{
    const float* Q  = (const float*)d_in[0];
    const float* K  = (const float*)d_in[1];
    const float* V  = (const float*)d_in[2];
    const float* Wq = (const float*)d_in[3];
    const float* bq = (const float*)d_in[4];
    const float* Wo = (const float*)d_in[5];
    const float* bo = (const float*)d_in[6];
    float* out = (float*)d_out;
    u16*   ws  = (u16*)d_ws;

    const size_t NBD = (size_t)B_ * N_ * D_;   // 4,194,304
    const int M = B_ * N_;                     // 8192

    u16* Qp  = ws;                // [b][n][d]
    u16* Kp  = ws + NBD;          // [b][n][d]
    u16* Vpt = ws + 2 * NBD;      // [b][d][n]

    const size_t need = (5 * NBD + 2 * (size_t)D_ * D_) * sizeof(u16); // 43.0 MB

    if (ws_size >= need) {
        u16* Pa  = ws + 3 * NBD;          // partial A, seg 0
        u16* Pb  = ws + 4 * NBD;          // partial A, seg 1
        u16* Wqb = ws + 5 * NBD;          // bf16 Wq
        u16* Wob = Wqb + (size_t)D_ * D_; // bf16 Wo

        wconv<<<dim3(128, 2), dim3(256), 0, stream>>>(Wq, Wo, Wqb);

        dim3 gp(D_ / 128, M / 128, 3);
        proj_mfma<0, true, true><<<gp, dim3(256), 0, stream>>>(
            Q, K, V, Wqb, bq, Qp, M);

        dim3 ga(N_ / 16, B_, 2);
        attn_mfma<2><<<ga, dim3(256), 0, stream>>>(Qp, Kp, Vpt, Pa);

        dim3 go(D_ / 128, M / 128, 1);
        proj_mfma<2, true, false><<<go, dim3(256), 0, stream>>>(
            Pa, Pb, Pb, Wob, bo, out, M);
    } else {
        // Fallback: proven 33.5 MB footprint, no split, in-kernel W convert.
        u16* Ap = ws + 3 * NBD;

        dim3 gp(D_ / 128, M / 128, 3);
        proj_mfma<0, false, true><<<gp, dim3(256), 0, stream>>>(
            Q, K, V, Wq, bq, Qp, M);

        dim3 ga(N_ / 16, B_, 1);
        attn_mfma<1><<<ga, dim3(256), 0, stream>>>(Qp, Kp, Vpt, Ap);

        dim3 go(D_ / 128, M / 128, 1);
        proj_mfma<1, false, false><<<go, dim3(256), 0, stream>>>(
            Ap, Ap, Ap, Wo, bo, out, M);
    }
}

// Round 8
// 327.987 us; speedup vs baseline: 1.3214x; 1.3006x over previous
//
#include <hip/hip_runtime.h>
#include <hip/hip_bf16.h>

// B,N,D,H = 4,2048,512,8 (DK=64). fp32 I/O; bf16 intermediates in ws.
// attn v3: 64 n-rows/block (4x less L2/L3 traffic than R5-R7's 2GB),
// in-register heads-softmax, XCD-pinned (b,seg) working sets.
#define B_  4
#define N_  2048
#define D_  512
#define H_  8

typedef unsigned short u16;
typedef __attribute__((ext_vector_type(8))) unsigned short ushort8;
typedef __attribute__((ext_vector_type(4))) unsigned short us4;
typedef __attribute__((ext_vector_type(8))) short short8;
typedef __attribute__((ext_vector_type(4))) float float4v;

__device__ __forceinline__ float bf2f(u16 u) {
    union { unsigned int i; float f; } v;
    v.i = ((unsigned int)u) << 16;
    return v.f;
}
__device__ __forceinline__ u16 f2bf(float f) {          // RNE
    union { float f; unsigned int i; } v;
    v.f = f;
    unsigned int r = v.i + 0x7FFFu + ((v.i >> 16) & 1u);
    return (u16)(r >> 16);
}
__device__ __forceinline__ u16 f2bf_fast(float f) {     // round-half-up
    union { float f; unsigned int i; } v;
    v.f = f;
    return (u16)((v.i + 0x8000u) >> 16);
}

// async global->LDS, 16B/lane, dest = wave-uniform base + lane*16 (m104 rule)
__device__ __forceinline__ void gload_lds16(const void* g, void* l) {
    __builtin_amdgcn_global_load_lds(
        (const __attribute__((address_space(1))) unsigned int*)g,
        (__attribute__((address_space(3))) unsigned int*)l, 16, 0, 0);
}

// ---------------------------------------------------------------------------
// wconv: Wq,Wo fp32 -> bf16, out = [Wqb | Wob]. grid (128, 2) x 256.
// ---------------------------------------------------------------------------
__global__ __launch_bounds__(256) void wconv(
    const float* __restrict__ Wq, const float* __restrict__ Wo,
    u16* __restrict__ out)
{
    const int idx = (blockIdx.x * 256 + threadIdx.x) * 8;
    const float* src = blockIdx.y ? Wo : Wq;
    u16* dst = out + (size_t)blockIdx.y * (D_ * D_) + idx;
    float4v a = *(const float4v*)(src + idx);
    float4v b = *(const float4v*)(src + idx + 4);
    ushort8 o;
    #pragma unroll
    for (int j = 0; j < 4; ++j) { o[j] = f2bf(a[j]); o[j + 4] = f2bf(b[j]); }
    *(ushort8*)dst = o;
}

// ---------------------------------------------------------------------------
// cvt3: Q,K,V fp32 -> bf16 slabs. grid (NBD/2048, 3) x 256.
// ---------------------------------------------------------------------------
__global__ __launch_bounds__(256) void cvt3(
    const float* __restrict__ Q, const float* __restrict__ K,
    const float* __restrict__ V, u16* __restrict__ out)
{
    const size_t NBD = (size_t)B_ * N_ * D_;
    const float* src = (blockIdx.y == 0) ? Q : ((blockIdx.y == 1) ? K : V);
    u16* dst = out + (size_t)blockIdx.y * NBD;
    size_t idx = ((size_t)blockIdx.x * 256 + threadIdx.x) * 8;
    float4v a = *(const float4v*)(src + idx);
    float4v b = *(const float4v*)(src + idx + 4);
    ushort8 o;
    #pragma unroll
    for (int j = 0; j < 4; ++j) { o[j] = f2bf(a[j]); o[j + 4] = f2bf(b[j]); }
    *(ushort8*)(dst + idx) = o;
}

// ---------------------------------------------------------------------------
// MFMA GEMM: C[M,512] = X @ W^T + bias.  1D grid, XCD swizzle: the 4 e-tiles
// of one (z,m) X-panel land on one XCD (flat&7 selects (z,m) low bits).
// INK: 0 = X fp32 (VALU cvt), 1 = X bf16 (gload), 2 = X0+X1 bf16 partials.
// WB16: W bf16 via gload. OUTB16: C bf16 (z==2 -> transposed Vpt[b][e][n]).
// 128x128 tile, 4 waves x 4x4 MFMA 16x16x32, BK=32.
// ---------------------------------------------------------------------------
template <int INK, bool WB16, bool OUTB16, int NZ>
__global__ __launch_bounds__(256) void proj_mfma(
    const void* __restrict__ X0v, const void* __restrict__ X1v,
    const void* __restrict__ X2v, const void* __restrict__ Wv,
    const float* __restrict__ bias, void* __restrict__ C0v, int M)
{
    __shared__ u16 As[128][32];
    __shared__ u16 Bs[128][32];

    const int t = threadIdx.x;
    // swizzle decode: flat = xcd + 8*(e + 4*g), zm = xcd + 8*g
    const int flat = blockIdx.x;
    const int xcd = flat & 7, rr = flat >> 3;
    const int eb = rr & 3, g = rr >> 2;
    const int zm = xcd + 8 * g;          // 0 .. 64*NZ-1
    const int z  = zm >> 6;
    const int e0 = eb * 128;
    const int m0 = (zm & 63) * 128;

    const void* Xv = (z == 0) ? X0v : ((z == 1) ? X1v : X2v);
    const int w = t >> 6, l = t & 63;
    const int lane16 = l & 15, quad = l >> 4;
    const int wr = (w >> 1) * 64;
    const int wc = (w & 1) * 64;

    float4v acc[4][4];
    #pragma unroll
    for (int i = 0; i < 4; ++i)
        #pragma unroll
        for (int j = 0; j < 4; ++j)
            acc[i][j] = (float4v){0.f, 0.f, 0.f, 0.f};

    for (int k0 = 0; k0 < 512; k0 += 32) {
        __syncthreads();

        // ---- stage A tile ----
        if (INK == 1) {
            const u16* X = (const u16*)Xv;
            #pragma unroll
            for (int i = 0; i < 2; ++i) {
                int r0 = w * 32 + i * 16;
                gload_lds16(X + (size_t)(m0 + r0 + (l >> 2)) * 512 + k0 + (l & 3) * 8,
                            &As[r0][0]);
            }
        } else if (INK == 0) {
            const float* X = (const float*)Xv;
            #pragma unroll
            for (int i = 0; i < 2; ++i) {
                int v   = t + 256 * i;
                int row = v >> 2;
                int c8  = (v & 3) * 8;
                const float* xp = X + (size_t)(m0 + row) * 512 + k0 + c8;
                float4v x0 = *(const float4v*)xp;
                float4v x1 = *(const float4v*)(xp + 4);
                ushort8 o;
                #pragma unroll
                for (int j = 0; j < 4; ++j) {
                    o[j]     = f2bf_fast(x0[j]);
                    o[j + 4] = f2bf_fast(x1[j]);
                }
                *(ushort8*)&As[row][c8] = o;
            }
        } else {  // INK == 2: sum of two bf16 partials
            const u16* P0 = (const u16*)X0v;
            const u16* P1 = (const u16*)X1v;
            #pragma unroll
            for (int i = 0; i < 2; ++i) {
                int v   = t + 256 * i;
                int row = v >> 2;
                int c8  = (v & 3) * 8;
                size_t gi = (size_t)(m0 + row) * 512 + k0 + c8;
                ushort8 a = *(const ushort8*)(P0 + gi);
                ushort8 b = *(const ushort8*)(P1 + gi);
                ushort8 o;
                #pragma unroll
                for (int j = 0; j < 8; ++j) o[j] = f2bf(bf2f(a[j]) + bf2f(b[j]));
                *(ushort8*)&As[row][c8] = o;
            }
        }

        // ---- stage B tile (W, bf16 via gload) ----
        if (WB16) {
            const u16* Wb = (const u16*)Wv;
            #pragma unroll
            for (int i = 0; i < 2; ++i) {
                int r0 = w * 32 + i * 16;
                gload_lds16(Wb + (size_t)(e0 + r0 + (l >> 2)) * 512 + k0 + (l & 3) * 8,
                            &Bs[r0][0]);
            }
        } else {
            const float* W = (const float*)Wv;
            #pragma unroll
            for (int i = 0; i < 2; ++i) {
                int v   = t + 256 * i;
                int row = v >> 2;
                int c8  = (v & 3) * 8;
                const float* wp = W + (size_t)(e0 + row) * 512 + k0 + c8;
                float4v w0 = *(const float4v*)wp;
                float4v w1 = *(const float4v*)(wp + 4);
                ushort8 o;
                #pragma unroll
                for (int j = 0; j < 4; ++j) {
                    o[j]     = f2bf_fast(w0[j]);
                    o[j + 4] = f2bf_fast(w1[j]);
                }
                *(ushort8*)&Bs[row][c8] = o;
            }
        }
        __syncthreads();

        short8 af[4], bfr[4];
        #pragma unroll
        for (int i = 0; i < 4; ++i)
            af[i] = *(const short8*)&As[wr + i * 16 + lane16][quad * 8];
        #pragma unroll
        for (int j = 0; j < 4; ++j)
            bfr[j] = *(const short8*)&Bs[wc + j * 16 + lane16][quad * 8];
        #pragma unroll
        for (int i = 0; i < 4; ++i)
            #pragma unroll
            for (int j = 0; j < 4; ++j)
                acc[i][j] = __builtin_amdgcn_mfma_f32_16x16x32_bf16(
                    af[i], bfr[j], acc[i][j], 0, 0, 0);
    }

    float bj[4];
    #pragma unroll
    for (int j = 0; j < 4; ++j) bj[j] = bias[e0 + wc + j * 16 + lane16];

    if (OUTB16) {
        if (z == 2) {   // transposed store: Vpt[b][e][n]
            u16* C = (u16*)C0v + 2 * (size_t)M * D_;
            #pragma unroll
            for (int i = 0; i < 4; ++i) {
                int mrow = m0 + wr + i * 16 + quad * 4;
                int bb = mrow >> 11, nb = mrow & (N_ - 1);
                #pragma unroll
                for (int j = 0; j < 4; ++j) {
                    int e = e0 + wc + j * 16 + lane16;
                    us4 o;
                    #pragma unroll
                    for (int r = 0; r < 4; ++r) o[r] = f2bf(acc[i][j][r] + bj[j]);
                    *(us4*)(C + (size_t)(bb * D_ + e) * N_ + nb) = o;
                }
            }
        } else {
            u16* C = (u16*)C0v + (size_t)z * (size_t)M * D_;
            #pragma unroll
            for (int i = 0; i < 4; ++i)
                #pragma unroll
                for (int j = 0; j < 4; ++j) {
                    int e = e0 + wc + j * 16 + lane16;
                    #pragma unroll
                    for (int r = 0; r < 4; ++r) {
                        int mrow = m0 + wr + i * 16 + quad * 4 + r;
                        C[(size_t)mrow * D_ + e] = f2bf(acc[i][j][r] + bj[j]);
                    }
                }
        }
    } else {
        float* C = (float*)C0v;
        #pragma unroll
        for (int i = 0; i < 4; ++i)
            #pragma unroll
            for (int j = 0; j < 4; ++j) {
                int e = e0 + wc + j * 16 + lane16;
                #pragma unroll
                for (int r = 0; r < 4; ++r) {
                    int mrow = m0 + wr + i * 16 + quad * 4 + r;
                    C[(size_t)mrow * D_ + e] = acc[i][j][r] + bj[j];
                }
            }
    }
}

// ---------------------------------------------------------------------------
// attn v3: heads-softmax in registers; 64 n-rows per block (4 waves x 16
// private rows). m-chunks of 32 staged in LDS (K via gload, V via regular
// loads into padded rows). Per chunk: 2 barriers; QK (32 MFMA) -> register
// softmax -> P to wave-private LDS (no barrier) -> PV (32 MFMA, k=32).
// SPLIT=2 m-halves -> bf16 partial A buffers. XCD pinning: flat&7 = (b,z).
// Qp,Kp: [b][n][d]. Vpt: [b][d][n]. grid = 8 * (N/64) = 256 blocks.
// ---------------------------------------------------------------------------
__global__ __launch_bounds__(256, 1) void attn_mfma3(
    const u16* __restrict__ Qp, const u16* __restrict__ Kp,
    const u16* __restrict__ Vpt, u16* __restrict__ A0)
{
    __shared__ u16 Ks[32][520];        // 33,280 B (pad: 2-way-free frag reads)
    __shared__ u16 Vs[512][40];        // 40,960 B (pad: 2-way-free frag reads)
    __shared__ u16 Ps[4][8][16][40];   // 40,960 B wave-private P regions

    const int t = threadIdx.x;
    const int w = t >> 6, l = t & 63;
    const int lane16 = l & 15, quad = l >> 4;

    const int flat = blockIdx.x;
    const int xcd  = flat & 7;
    const int b = xcd >> 1;            // (b, z) pinned to one XCD
    const int z = xcd & 1;
    const int n0 = (flat >> 3) * 64 + w * 16;   // wave-private 16 rows
    const int seg  = N_ / 2;
    const int mbeg = z * seg;
    u16* A = A0 + (size_t)z * ((size_t)B_ * N_ * D_);

    // Q fragments: 8 heads x k=64, A-operand layout, persistent (64 VGPRs)
    short8 qfrag[8][2];
    {
        const u16* qb = Qp + ((size_t)(b * N_ + n0 + lane16) * D_ + quad * 8);
        #pragma unroll
        for (int h = 0; h < 8; ++h)
            #pragma unroll
            for (int dc = 0; dc < 2; ++dc)
                qfrag[h][dc] = *(const short8*)(qb + h * 64 + dc * 32);
    }

    float4v aacc[8][4];                // 8 heads x 4 d-tiles (128 VGPRs)
    #pragma unroll
    for (int h = 0; h < 8; ++h)
        #pragma unroll
        for (int dt = 0; dt < 4; ++dt)
            aacc[h][dt] = (float4v){0.f, 0.f, 0.f, 0.f};

    for (int mc = mbeg; mc < mbeg + seg; mc += 32) {
        __syncthreads();   // prev chunk's Ks/Vs reads complete

        // ---- stage K: 32 rows x 1KB via gload ----
        #pragma unroll
        for (int i = 0; i < 8; ++i) {
            int row = w * 8 + i;
            gload_lds16(Kp + (size_t)(b * N_ + mc + row) * D_ + l * 8, &Ks[row][0]);
        }
        // ---- stage V: 512 d-rows x 32 m (padded rows -> regular loads) ----
        #pragma unroll
        for (int i = 0; i < 8; ++i) {
            int v = i * 256 + t;
            int d = v >> 2, part = v & 3;
            ushort8 x = *(const ushort8*)(Vpt + (size_t)(b * D_ + d) * N_ + mc + part * 8);
            *(ushort8*)&Vs[d][part * 8] = x;
        }
        __syncthreads();   // staging visible

        // ---- QK^T (8 heads) + register softmax, per 16-m subtile ----
        #pragma unroll
        for (int msub = 0; msub < 2; ++msub) {
            float4v sacc[8];
            #pragma unroll
            for (int h = 0; h < 8; ++h) sacc[h] = (float4v){0.f, 0.f, 0.f, 0.f};
            #pragma unroll
            for (int h = 0; h < 8; ++h)
                #pragma unroll
                for (int dc = 0; dc < 2; ++dc) {
                    short8 kf = *(const short8*)
                        &Ks[msub * 16 + lane16][h * 64 + dc * 32 + quad * 8];
                    sacc[h] = __builtin_amdgcn_mfma_f32_16x16x32_bf16(
                        qfrag[h][dc], kf, sacc[h], 0, 0, 0);
                }
            #pragma unroll
            for (int r = 0; r < 4; ++r) {
                float p[8]; float sum = 0.f;
                #pragma unroll
                for (int h = 0; h < 8; ++h) {
                    p[h] = __expf(sacc[h][r] * 0.125f);   // 1/sqrt(64)
                    sum += p[h];
                }
                float inv = 1.f / sum;
                #pragma unroll
                for (int h = 0; h < 8; ++h)
                    Ps[w][h][quad * 4 + r][msub * 16 + lane16] = f2bf(p[h] * inv);
            }
        }

        // ---- PV: wave-private P (lgkmcnt ordering, no barrier), k=32 ----
        #pragma unroll
        for (int h = 0; h < 8; ++h) {
            short8 pf = *(const short8*)&Ps[w][h][lane16][quad * 8];
            #pragma unroll
            for (int dt = 0; dt < 4; ++dt) {
                short8 vf = *(const short8*)
                    &Vs[h * 64 + dt * 16 + lane16][quad * 8];
                aacc[h][dt] = __builtin_amdgcn_mfma_f32_16x16x32_bf16(
                    pf, vf, aacc[h][dt], 0, 0, 0);
            }
        }
    }

    // ---- store partial A (bf16) ----
    #pragma unroll
    for (int h = 0; h < 8; ++h)
        #pragma unroll
        for (int dt = 0; dt < 4; ++dt)
            #pragma unroll
            for (int r = 0; r < 4; ++r) {
                const int n = n0 + quad * 4 + r;
                const int d = h * 64 + dt * 16 + lane16;
                A[(size_t)(b * N_ + n) * D_ + d] = f2bf(aacc[h][dt][r]);
            }
}

// ---------------------------------------------------------------------------
extern "C" void kernel_launch(void* const* d_in, const int* in_sizes, int n_in,
                              void* d_out, int out_size, void* d_ws, size_t ws_size,
                              hipStream_t stream)
{
    const float* Q  = (const float*)d_in[0];
    const float* K  = (const float*)d_in[1];
    const float* V  = (const float*)d_in[2];
    const float* Wq = (const float*)d_in[3];
    const float* bq = (const float*)d_in[4];
    const float* Wo = (const float*)d_in[5];
    const float* bo = (const float*)d_in[6];
    float* out = (float*)d_out;
    u16*   ws  = (u16*)d_ws;

    const size_t NBD = (size_t)B_ * N_ * D_;   // 4,194,304
    const int M = B_ * N_;                     // 8192

    const size_t need6 = (6 * NBD + 2 * (size_t)D_ * D_) * sizeof(u16); // 51.4 MB

    if (ws_size >= need6) {
        // Path A: bf16-ify inputs once; proj1 all-gload. Slab reuse:
        // S0=Qb->Pa, S1=Kb->Pb, S2=Vb, S3=Qp, S4=Kp, S5=Vpt, then Wb.
        u16* S0 = ws;
        u16* S1 = ws + NBD;
        u16* S2 = ws + 2 * NBD;
        u16* S3 = ws + 3 * NBD;
        u16* Wb = ws + 6 * NBD;            // [Wqb | Wob]

        cvt3<<<dim3((unsigned)(NBD / 2048), 3), dim3(256), 0, stream>>>(Q, K, V, S0);
        wconv<<<dim3(128, 2), dim3(256), 0, stream>>>(Wq, Wo, Wb);

        proj_mfma<1, true, true, 3><<<dim3(768), dim3(256), 0, stream>>>(
            S0, S1, S2, Wb, bq, S3, M);    // -> Qp(S3), Kp(S4), Vpt(S5)

        attn_mfma3<<<dim3(256), dim3(256), 0, stream>>>(
            S3, S3 + NBD, S3 + 2 * NBD, S0);   // partials -> S0, S1

        proj_mfma<2, true, false, 1><<<dim3(256), dim3(256), 0, stream>>>(
            S0, S1, S1, Wb + (size_t)D_ * D_, bo, out, M);
    } else {
        // Path B (proven 43.0 MB): fp32-X staging in proj1.
        u16* Qp  = ws;
        u16* Kp  = ws + NBD;
        u16* Vpt = ws + 2 * NBD;
        u16* Pa  = ws + 3 * NBD;
        u16* Pb  = ws + 4 * NBD;
        u16* Wb  = ws + 5 * NBD;

        wconv<<<dim3(128, 2), dim3(256), 0, stream>>>(Wq, Wo, Wb);

        proj_mfma<0, true, true, 3><<<dim3(768), dim3(256), 0, stream>>>(
            Q, K, V, Wb, bq, Qp, M);

        attn_mfma3<<<dim3(256), dim3(256), 0, stream>>>(Qp, Kp, Vpt, Pa);

        proj_mfma<2, true, false, 1><<<dim3(256), dim3(256), 0, stream>>>(
            Pa, Pb, Pb, Wb + (size_t)D_ * D_, bo, out, M);
    }
}